// Round 16
// baseline (1204.602 us; speedup 1.0000x reference)
//
#include <hip/hip_runtime.h>
#include <hip/hip_bf16.h>
#include <cstdint>
#include <cstddef>

typedef float    f32x4  __attribute__((ext_vector_type(4)));
typedef _Float16 f16x4  __attribute__((ext_vector_type(4)));
typedef _Float16 f16x8  __attribute__((ext_vector_type(8)));

#define BN_G1 1024   // stage-1 grid for standalone bn stats

// ---------------- graph structure ----------------
__global__ void k_hist(const int* __restrict__ dst, int* __restrict__ deg, int E,
                       unsigned long long M,
                       const int* __restrict__ batch, int* __restrict__ cnt, int n){
  __shared__ int h[64];
  if(threadIdx.x<64) h[threadIdx.x]=0;
  __syncthreads();
  int f   = blockIdx.x & 7;
  int cid = blockIdx.x >> 3;
  int nch = gridDim.x >> 3;
  for(int i = cid*blockDim.x + threadIdx.x; i < E; i += nch*blockDim.x){
    int d = dst[i];
    int xf = (int)(((unsigned long long)(unsigned)d * M) >> 40);
    if(xf == f) atomicAdd(&deg[d], 1);
  }
  for(int i = blockIdx.x*blockDim.x + threadIdx.x; i < n; i += gridDim.x*blockDim.x)
    atomicAdd(&h[batch[i]], 1);
  __syncthreads();
  if(threadIdx.x<64 && h[threadIdx.x]) atomicAdd(&cnt[threadIdx.x], h[threadIdx.x]);
}

__global__ void k_scan1(const int* __restrict__ deg, int* __restrict__ bsum, int n){
  __shared__ int s[256];
  int base = blockIdx.x*1024 + threadIdx.x*4;
  int acc=0;
  #pragma unroll
  for(int j=0;j<4;j++){ int i=base+j; if(i<n) acc+=deg[i]; }
  s[threadIdx.x]=acc; __syncthreads();
  for(int off=128;off>0;off>>=1){
    if(threadIdx.x<off) s[threadIdx.x]+=s[threadIdx.x+off];
    __syncthreads();
  }
  if(threadIdx.x==0) bsum[blockIdx.x]=s[0];
}

__global__ void k_scan2(int* __restrict__ bsum, int nblk, int* __restrict__ rowptr, int n){
  __shared__ int s[128];
  int t=threadIdx.x;
  int v = (t<nblk)? bsum[t] : 0;
  s[t]=v; __syncthreads();
  for(int off=1; off<128; off<<=1){
    int a = (t>=off)? s[t-off] : 0;
    __syncthreads();
    s[t]+=a;
    __syncthreads();
  }
  if(t<nblk) bsum[t]=s[t]-v;
  if(t==127) rowptr[n]=s[127];
}

__global__ void k_scan3(const int* __restrict__ deg, const int* __restrict__ bsum,
                        int* __restrict__ rowptr, int* __restrict__ cursor, int n){
  __shared__ int s[256];
  int base = blockIdx.x*1024 + threadIdx.x*4;
  int v[4]; int acc=0;
  #pragma unroll
  for(int j=0;j<4;j++){ int i=base+j; v[j]=(i<n)?deg[i]:0; acc+=v[j]; }
  s[threadIdx.x]=acc; __syncthreads();
  for(int off=1; off<256; off<<=1){
    int a = (threadIdx.x>=off)? s[threadIdx.x-off] : 0;
    __syncthreads();
    s[threadIdx.x]+=a;
    __syncthreads();
  }
  int excl = s[threadIdx.x]-acc + bsum[blockIdx.x];
  #pragma unroll
  for(int j=0;j<4;j++){
    int i=base+j;
    if(i<n){ rowptr[i]=excl; cursor[i]=excl; excl+=v[j]; }
  }
}

__global__ void k_csr_fill(const int* __restrict__ src, const int* __restrict__ dst,
                           int* __restrict__ cursor, int* __restrict__ adj, int E,
                           unsigned long long M){
  int f   = blockIdx.x & 7;
  int cid = blockIdx.x >> 3;
  int nch = gridDim.x >> 3;
  for(int i = cid*blockDim.x + threadIdx.x; i < E; i += nch*blockDim.x){
    int d = dst[i];
    int xf = (int)(((unsigned long long)(unsigned)d * M) >> 40);
    if(xf == f){
      int p = atomicAdd(&cursor[d], 1);
      adj[p] = src[i];
    }
  }
}

// ---------------- fused prep: W hi/lo split (3 mats) + dinv + x16 ----------------
__global__ void k_prep(const float* __restrict__ W0, const float* __restrict__ W1,
                       const float* __restrict__ W2,
                       _Float16* __restrict__ Wh0, _Float16* __restrict__ Wl0,
                       _Float16* __restrict__ Wh1, _Float16* __restrict__ Wl1,
                       _Float16* __restrict__ Wh2, _Float16* __restrict__ Wl2,
                       const float* __restrict__ x, const int* __restrict__ deg,
                       float* __restrict__ dinv, _Float16* __restrict__ x16, int n){
  int i = blockIdx.x*256 + threadIdx.x;
  if(i < 73728){
    const float* W; _Float16 *Wh, *Wl; int K, F, idx;
    if(i < 32768){        W=W0; Wh=Wh0; Wl=Wl0; K=128; F=256; idx=i; }
    else if(i < 65536){   W=W1; Wh=Wh1; Wl=Wl1; K=256; F=128; idx=i-32768; }
    else {                W=W2; Wh=Wh2; Wl=Wl2; K=128; F=64;  idx=i-65536; }
    int k = idx / F, f = idx % F;
    float a = W[idx];
    _Float16 h = (_Float16)a;
    Wh[(size_t)f*K + k] = h;
    Wl[(size_t)f*K + k] = (_Float16)(a - (float)h);
    return;
  }
  int tid = i - 73728;
  int node = tid >> 5;
  if(node>=n) return;
  int c4 = tid & 31;
  float d = rsqrtf((float)(deg[node]+1));
  if(c4==0) dinv[node] = d;
  size_t idx = ((size_t)node<<5) + c4;
  float4 v = ((const float4*)x)[idx];
  f16x4 o;
  o[0]=(_Float16)(v.x*d); o[1]=(_Float16)(v.y*d); o[2]=(_Float16)(v.z*d); o[3]=(_Float16)(v.w*d);
  ((f16x4*)x16)[idx] = o;
}

// ---------------- aggregate (fp16 gather, fp32 accum, fp16 out; barrier-free) ----------------
__global__ void k_agg16(const _Float16* __restrict__ zs, const int* __restrict__ rowptr,
                        const int* __restrict__ adj, const float* __restrict__ dinv,
                        const float* __restrict__ bias, _Float16* __restrict__ out,
                        int n, int lg8){
  int tid = blockIdx.x*blockDim.x + threadIdx.x;
  int node = tid >> lg8;
  if(node>=n) return;
  int c8 = tid & ((1<<lg8)-1);
  const f16x8* z8 = (const f16x8*)zs;
  size_t rb = ((size_t)node<<lg8) + c8;
  f16x8 self = z8[rb];
  float a0[8], a1[8], a2[8], a3[8];
  #pragma unroll
  for(int j=0;j<8;j++){ a0[j]=(float)self[j]; a1[j]=0.f; a2[j]=0.f; a3[j]=0.f; }
  int e = rowptr[node], end = rowptr[node+1];
  for(; e+3<end; e+=4){
    int s0=adj[e], s1=adj[e+1], s2=adj[e+2], s3=adj[e+3];
    f16x8 v0 = z8[((size_t)s0<<lg8)+c8];
    f16x8 v1 = z8[((size_t)s1<<lg8)+c8];
    f16x8 v2 = z8[((size_t)s2<<lg8)+c8];
    f16x8 v3 = z8[((size_t)s3<<lg8)+c8];
    #pragma unroll
    for(int j=0;j<8;j++){
      a0[j]+=(float)v0[j]; a1[j]+=(float)v1[j];
      a2[j]+=(float)v2[j]; a3[j]+=(float)v3[j];
    }
  }
  for(; e<end; e++){
    f16x8 v0 = z8[((size_t)adj[e]<<lg8)+c8];
    #pragma unroll
    for(int j=0;j<8;j++) a0[j]+=(float)v0[j];
  }
  float di = dinv[node];
  f16x8 o;
  #pragma unroll
  for(int j=0;j<8;j++){
    float r = ((a0[j]+a1[j])+(a2[j]+a3[j]))*di;
    if(bias) r += bias[(c8<<3)+j];
    o[j] = (_Float16)r;
  }
  ((f16x8*)out)[rb] = o;
}

// ---------------- MFMA GEMM: f16 A, f16 hi/lo B, LDS-staged B, optional fused stats ----------------
template<int K, int F, bool BN, bool BIAS, bool RSC, bool STATS>
__global__ __launch_bounds__(256,2) void k_gemm_mfma(const _Float16* __restrict__ A,
    const _Float16* __restrict__ Bh, const _Float16* __restrict__ Bl,
    const float* __restrict__ sc, const float* __restrict__ sh,
    const float* __restrict__ bias, const float* __restrict__ rsc,
    _Float16* __restrict__ C, float* __restrict__ partials, int n){
  constexpr int NF = F/16;
  __shared__ uint4 sBh[F*4];
  __shared__ uint4 sBl[F*4];
  const int l   = threadIdx.x & 63;
  const int w   = threadIdx.x >> 6;
  const int rlo = l & 15;
  const int khi = l >> 4;
  const int row0 = blockIdx.x*128 + w*32;

  f32x4 acc[2][NF];
  #pragma unroll
  for(int i=0;i<2;i++)
    #pragma unroll
    for(int j=0;j<NF;j++) acc[i][j] = (f32x4){0.f,0.f,0.f,0.f};

  const size_t e0 = (size_t)min(row0 + rlo,      n-1) * K + khi*8;
  const size_t e1 = (size_t)min(row0 + 16 + rlo, n-1) * K + khi*8;

  f16x8 c0 = *(const f16x8*)(A + e0);
  f16x8 c1 = *(const f16x8*)(A + e1);
  f16x8 n0v, n1v;

  #pragma unroll 1
  for(int k0=0; k0<K; k0+=32){
    if(k0+32 < K){
      n0v = *(const f16x8*)(A + e0 + k0 + 32);
      n1v = *(const f16x8*)(A + e1 + k0 + 32);
    }
    __syncthreads();
    #pragma unroll
    for(int j=0;j<F/64;j++){
      int i  = threadIdx.x + j*256;
      int f  = i >> 2;
      int k8 = i & 3;
      int g  = ((f>>4)<<6) + (k8<<4) + (f&15);
      size_t goff = (size_t)f*K + k0 + (k8<<3);
      sBh[g] = *(const uint4*)(Bh + goff);
      sBl[g] = *(const uint4*)(Bl + goff);
    }
    f16x8 a0, a1;
    if(BN){
      float scr[8], shr[8];
      float4 s0 = *(const float4*)(sc + k0 + khi*8);
      float4 s1 = *(const float4*)(sc + k0 + khi*8 + 4);
      float4 t0 = *(const float4*)(sh + k0 + khi*8);
      float4 t1 = *(const float4*)(sh + k0 + khi*8 + 4);
      scr[0]=s0.x;scr[1]=s0.y;scr[2]=s0.z;scr[3]=s0.w;scr[4]=s1.x;scr[5]=s1.y;scr[6]=s1.z;scr[7]=s1.w;
      shr[0]=t0.x;shr[1]=t0.y;shr[2]=t0.z;shr[3]=t0.w;shr[4]=t1.x;shr[5]=t1.y;shr[6]=t1.z;shr[7]=t1.w;
      #pragma unroll
      for(int j=0;j<8;j++){
        a0[j] = (_Float16)fmaxf(fmaf((float)c0[j],scr[j],shr[j]),0.f);
        a1[j] = (_Float16)fmaxf(fmaf((float)c1[j],scr[j],shr[j]),0.f);
      }
    }else{
      a0 = c0; a1 = c1;
    }
    __syncthreads();
    #pragma unroll
    for(int cf=0; cf<NF; cf++){
      f16x8 bh = ((const f16x8*)sBh)[cf*64 + l];
      f16x8 bl = ((const f16x8*)sBl)[cf*64 + l];
      acc[0][cf] = __builtin_amdgcn_mfma_f32_16x16x32_f16(a0, bh, acc[0][cf], 0,0,0);
      acc[1][cf] = __builtin_amdgcn_mfma_f32_16x16x32_f16(a1, bh, acc[1][cf], 0,0,0);
      acc[0][cf] = __builtin_amdgcn_mfma_f32_16x16x32_f16(a0, bl, acc[0][cf], 0,0,0);
      acc[1][cf] = __builtin_amdgcn_mfma_f32_16x16x32_f16(a1, bl, acc[1][cf], 0,0,0);
    }
    c0=n0v; c1=n1v;
  }

  float ts[NF], ts2[NF];
  if constexpr(STATS){
    #pragma unroll
    for(int cf=0;cf<NF;cf++){ ts[cf]=0.f; ts2[cf]=0.f; }
  }
  #pragma unroll
  for(int rf=0; rf<2; rf++){
    #pragma unroll
    for(int r=0; r<4; r++){
      int m = row0 + rf*16 + khi*4 + r;
      if(m < n){
        float rscv = RSC ? rsc[m] : 1.f;
        #pragma unroll
        for(int cf=0; cf<NF; cf++){
          int col = rlo + 16*cf;
          float v = acc[rf][cf][r];
          if(BIAS) v += bias[col];
          v *= rscv;
          C[(size_t)m*F + col] = (_Float16)v;
          if constexpr(STATS){ ts[cf]+=v; ts2[cf]=fmaf(v,v,ts2[cf]); }
        }
      }
    }
  }
  if constexpr(STATS){
    __shared__ float sstat[4][16][NF][2];
    #pragma unroll
    for(int cf=0;cf<NF;cf++){
      ts [cf] += __shfl_xor(ts [cf],16); ts [cf] += __shfl_xor(ts [cf],32);
      ts2[cf] += __shfl_xor(ts2[cf],16); ts2[cf] += __shfl_xor(ts2[cf],32);
    }
    if(khi==0){
      #pragma unroll
      for(int cf=0;cf<NF;cf++){ sstat[w][rlo][cf][0]=ts[cf]; sstat[w][rlo][cf][1]=ts2[cf]; }
    }
    __syncthreads();
    {
      int rl = threadIdx.x & 15, cf = threadIdx.x >> 4;
      float s_=0.f, s2_=0.f;
      #pragma unroll
      for(int ww=0; ww<4; ww++){ s_+=sstat[ww][rl][cf][0]; s2_+=sstat[ww][rl][cf][1]; }
      int col = rl + 16*cf;
      partials[(size_t)blockIdx.x*(2*F) + col]     = s_;
      partials[(size_t)blockIdx.x*(2*F) + F + col] = s2_;
    }
  }
}

// ---------------- standalone BN stats (fp16 in, per-block partials out) ----------------
__global__ __launch_bounds__(256) void k_bn_stats16(const _Float16* __restrict__ h,
                            float* __restrict__ partials, int n, int lgF){
  const int F   = 1 << lgF;
  const int C8  = 1 << (lgF-3);
  const int c8  = threadIdx.x & (C8-1);
  const int sub = threadIdx.x >> (lgF-3);
  const int rpb = 256 >> (lgF-3);
  float s[8], s2[8];
  #pragma unroll
  for(int j=0;j<8;j++){ s[j]=0.f; s2[j]=0.f; }
  for(int row = blockIdx.x*rpb + sub; row < n; row += gridDim.x*rpb){
    f16x8 v = ((const f16x8*)h)[(size_t)row*C8 + c8];
    #pragma unroll
    for(int j=0;j<8;j++){ float f=(float)v[j]; s[j]+=f; s2[j]=fmaf(f,f,s2[j]); }
  }
  __shared__ float rs [256*9];
  __shared__ float rs2[256*9];
  #pragma unroll
  for(int j=0;j<8;j++){ rs[threadIdx.x*9+j]=s[j]; rs2[threadIdx.x*9+j]=s2[j]; }
  __syncthreads();
  for(int half = rpb>>1; half>=1; half>>=1){
    if(sub < half){
      int o = (threadIdx.x + half*C8)*9;
      #pragma unroll
      for(int j=0;j<8;j++){ rs[threadIdx.x*9+j]+=rs[o+j]; rs2[threadIdx.x*9+j]+=rs2[o+j]; }
    }
    __syncthreads();
  }
  if(sub==0){
    float* p = partials + (size_t)blockIdx.x*(2*F);
    #pragma unroll
    for(int j=0;j<8;j++){
      p[c8*8+j]     = rs [threadIdx.x*9+j];
      p[F + c8*8+j] = rs2[threadIdx.x*9+j];
    }
  }
}

// ---------------- fused BN reduce + finalize: grid F/64, block 64 ----------------
__global__ void k_bn_fin(const float* __restrict__ partials, int F, int nblk,
                         const float* __restrict__ g, const float* __restrict__ be,
                         float* __restrict__ scale, float* __restrict__ shift, int n){
  int c = blockIdx.x*64 + threadIdx.x;
  int F2 = 2*F;
  float s=0.f, s2=0.f;
  for(int b=0; b<nblk; b++){
    const float* p = partials + (size_t)b*F2;
    s  += p[c];
    s2 += p[F + c];
  }
  float mu = s/(float)n;
  float var = s2/(float)n - mu*mu;
  float sc = g[c]*rsqrtf(var+1e-5f);
  scale[c] = sc;
  shift[c] = fmaf(-mu, sc, be[c]);
}

// ---------------- head ----------------
__device__ __forceinline__ float attw(float a){
  float t = fminf(fmaxf(a,-15.f),15.f);
  float u = exp2f(t*2.885390082f);
  float th = (u-1.f)/(u+1.f);
  return exp2f(th*1.442695041f);
}

__global__ void k_ln_att(const _Float16* __restrict__ x, const float* __restrict__ bsc, const float* __restrict__ bsh,
                         const float* __restrict__ g, const float* __restrict__ b,
                         const float* __restrict__ att, _Float16* __restrict__ lnx, float* __restrict__ wv,
                         float* __restrict__ Ssum, int n){
  int lane = threadIdx.x & 63;
  int wid = (blockIdx.x<<2) + (threadIdx.x>>6);
  float gl=g[lane], bl=b[lane], al=att[lane];
  float scl=bsc[lane], shl=bsh[lane];
  float wacc=0.f;
  int node = wid;
  for(; node+4096 < n; node += 8192){
    int n1 = node + 4096;
    float v0 = fmaxf(fmaf((float)x[((size_t)node<<6)+lane], scl, shl), 0.f);
    float v1 = fmaxf(fmaf((float)x[((size_t)n1  <<6)+lane], scl, shl), 0.f);
    float s0=v0, s1=v1;
    #pragma unroll
    for(int o=32;o>0;o>>=1){ s0+=__shfl_xor(s0,o); s1+=__shfl_xor(s1,o); }
    float d0=v0-s0*0.015625f, d1=v1-s1*0.015625f;
    float q0=d0*d0, q1=d1*d1;
    #pragma unroll
    for(int o=32;o>0;o>>=1){ q0+=__shfl_xor(q0,o); q1+=__shfl_xor(q1,o); }
    float ln0 = d0*rsqrtf(q0*0.015625f+1e-5f)*gl+bl;
    float ln1 = d1*rsqrtf(q1*0.015625f+1e-5f)*gl+bl;
    lnx[((size_t)node<<6)+lane]=(_Float16)ln0;
    lnx[((size_t)n1  <<6)+lane]=(_Float16)ln1;
    float a0=ln0*al, a1=ln1*al;
    #pragma unroll
    for(int o=32;o>0;o>>=1){ a0+=__shfl_xor(a0,o); a1+=__shfl_xor(a1,o); }
    float w0=attw(a0), w1=attw(a1);
    if(lane==0){ wv[node]=w0; wv[n1]=w1; }
    wacc += w0+w1;
  }
  for(; node<n; node+=4096){
    float v0 = fmaxf(fmaf((float)x[((size_t)node<<6)+lane], scl, shl), 0.f);
    float s0=v0;
    #pragma unroll
    for(int o=32;o>0;o>>=1) s0+=__shfl_xor(s0,o);
    float d0=v0-s0*0.015625f;
    float q0=d0*d0;
    #pragma unroll
    for(int o=32;o>0;o>>=1) q0+=__shfl_xor(q0,o);
    float ln0 = d0*rsqrtf(q0*0.015625f+1e-5f)*gl+bl;
    lnx[((size_t)node<<6)+lane]=(_Float16)ln0;
    float a0=ln0*al;
    #pragma unroll
    for(int o=32;o>0;o>>=1) a0+=__shfl_xor(a0,o);
    float w0=attw(a0);
    if(lane==0) wv[node]=w0;
    wacc += w0;
  }
  __shared__ float sred[4];
  if(lane==0) sred[threadIdx.x>>6]=wacc;
  __syncthreads();
  if(threadIdx.x==0) atomicAdd(Ssum, sred[0]+sred[1]+sred[2]+sred[3]);
}

__global__ void k_pool(const _Float16* __restrict__ lnx, const float* __restrict__ wv,
                       const int* __restrict__ batch, float* __restrict__ psum, int n){
  int lane = threadIdx.x & 63;
  int wave = threadIdx.x >> 6;
  int start = blockIdx.x*512 + wave*128;
  if(start >= n) return;
  int end = min(start+128, n);
  int cur = batch[start];
  float acc = 0.f;
  for(int i=start;i<end;i++){
    int bb = batch[i];
    if(bb != cur){ atomicAdd(&psum[cur*64+lane], acc); acc=0.f; cur=bb; }
    acc = fmaf((float)lnx[(size_t)i*64+lane], wv[i], acc);
  }
  atomicAdd(&psum[cur*64+lane], acc);
}

__global__ void k_mlp(const float* __restrict__ psum, const int* __restrict__ cnt,
                      const float* __restrict__ Ssum,
                      const float* __restrict__ M0W, const float* __restrict__ M0b,
                      const float* __restrict__ M1W, const float* __restrict__ M1b,
                      const float* __restrict__ M2W, const float* __restrict__ M2b,
                      float* __restrict__ out){
  int b = threadIdx.x;
  float S = Ssum[0];
  int cb = cnt[b]; if(cb<1) cb=1;
  float inv = 1.f/(S*(float)cb);
  float p[64];
  #pragma unroll
  for(int f=0;f<64;f++) p[f] = psum[b*64+f]*inv;
  float h1[32];
  #pragma unroll
  for(int j=0;j<32;j++){
    float a=M0b[j];
    #pragma unroll
    for(int f=0;f<64;f++) a = fmaf(p[f], M0W[f*32+j], a);
    h1[j]=fmaxf(a,0.f);
  }
  float h2[16];
  #pragma unroll
  for(int j=0;j<16;j++){
    float a=M1b[j];
    #pragma unroll
    for(int f=0;f<32;f++) a = fmaf(h1[f], M1W[f*16+j], a);
    h2[j]=fmaxf(a,0.f);
  }
  #pragma unroll
  for(int j=0;j<2;j++){
    float a=M2b[j];
    #pragma unroll
    for(int f=0;f<16;f++) a = fmaf(h2[f], M2W[f*2+j], a);
    out[b*2+j]=a;
  }
}

// ---------------- launch ----------------

extern "C" void kernel_launch(void* const* d_in, const int* in_sizes, int n_in,
                              void* d_out, int out_size, void* d_ws, size_t ws_size,
                              hipStream_t stream){
  const float* x   = (const float*)d_in[0];
  const int*   ei  = (const int*)d_in[1];
  const int* batch = (const int*)d_in[2];
  const float* W0=(const float*)d_in[3],  *b0=(const float*)d_in[4],  *g0=(const float*)d_in[5],  *be0=(const float*)d_in[6];
  const float* W1=(const float*)d_in[7],  *b1=(const float*)d_in[8],  *g1=(const float*)d_in[9],  *be1=(const float*)d_in[10];
  const float* W2=(const float*)d_in[11], *b2=(const float*)d_in[12], *g2=(const float*)d_in[13], *be2=(const float*)d_in[14];
  const float* ln_g=(const float*)d_in[15], *ln_b=(const float*)d_in[16], *att=(const float*)d_in[17];
  const float* M0W=(const float*)d_in[18], *M0b=(const float*)d_in[19];
  const float* M1W=(const float*)d_in[20], *M1b=(const float*)d_in[21];
  const float* M2W=(const float*)d_in[22], *M2b=(const float*)d_in[23];
  const int N = in_sizes[0]/128;
  const int E = in_sizes[1]/2;
  const int* srcv = ei;
  const int* dstv = ei + E;
  const unsigned long long Mdiv = ((8ULL<<40) + (unsigned long long)N - 1) / (unsigned long long)N;

  const int gemm_grid = (N+127)/128;

  char* base = (char*)d_ws;
  size_t off = 0;
  auto alloc = [&](size_t bytes)->char*{ char* p = base+off; off = (off+bytes+255)&~(size_t)255; return p; };
  // zeroed region first
  int*   deg    = (int*)  alloc((size_t)N*4);
  int*   cnt    = (int*)  alloc(64*4);
  float* psum   = (float*)alloc(64*64*4);
  float* Ssum   = (float*)alloc(4);
  size_t zero_bytes = off;
  float* dinv   = (float*)alloc((size_t)N*4);
  int*   rowptr = (int*)  alloc(((size_t)N+1)*4);
  int*   cursor = (int*)  alloc((size_t)N*4);
  int*   bsum   = (int*)  alloc(128*4);
  float* bnsc   = (float*)alloc(3*256*4);
  float* bnsh   = (float*)alloc(3*256*4);
  float* partials = (float*)alloc((size_t)BN_G1*512*4);
  _Float16* Wh0 = (_Float16*)alloc((size_t)128*256*2);
  _Float16* Wl0 = (_Float16*)alloc((size_t)128*256*2);
  _Float16* Wh1 = (_Float16*)alloc((size_t)256*128*2);
  _Float16* Wl1 = (_Float16*)alloc((size_t)256*128*2);
  _Float16* Wh2 = (_Float16*)alloc((size_t)128*64*2);
  _Float16* Wl2 = (_Float16*)alloc((size_t)128*64*2);
  int*   adj    = (int*)  alloc((size_t)E*4);
  _Float16* x16 = (_Float16*)alloc((size_t)N*128*2);
  _Float16* R16 = (_Float16*)alloc((size_t)N*128*2);
  _Float16* P16 = (_Float16*)alloc((size_t)N*256*2);
  _Float16* Q16 = (_Float16*)alloc((size_t)N*128*2);
  _Float16* O16 = (_Float16*)alloc((size_t)N*64*2);
  _Float16* LNX = (_Float16*)alloc((size_t)N*64*2);
  float* WV     = (float*)alloc((size_t)N*4);
  (void)ws_size; (void)n_in; (void)out_size;

  hipMemsetAsync(d_ws, 0, zero_bytes, stream);

  // graph structure + fused prep
  k_hist <<<2048,256,0,stream>>>(dstv, deg, E, Mdiv, batch, cnt, N);
  k_prep <<<(73728 + N*32 + 255)/256,256,0,stream>>>(W0,W1,W2, Wh0,Wl0, Wh1,Wl1, Wh2,Wl2,
                                                     x, deg, dinv, x16, N);
  int nblk = (N+1023)/1024;
  k_scan1<<<nblk,256,0,stream>>>(deg, bsum, N);
  k_scan2<<<1,128,0,stream>>>(bsum, nblk, rowptr, N);
  k_scan3<<<nblk,256,0,stream>>>(deg, bsum, rowptr, cursor, N);
  k_csr_fill<<<2048,256,0,stream>>>(srcv, dstv, cursor, adj, E, Mdiv);

  // ---- layer 0: agg -> GEMM0(+fused stats) -> fin ----
  k_agg16<<<(N*16+255)/256,256,0,stream>>>(x16, rowptr, adj, dinv, nullptr, R16, N, 4);
  k_gemm_mfma<128,256,false,true,false,true><<<gemm_grid,256,0,stream>>>(R16, Wh0, Wl0, nullptr,nullptr, b0, nullptr, P16, partials, N);
  k_bn_fin<<<4,64,0,stream>>>(partials, 256, gemm_grid, g0, be0, bnsc+0, bnsh+0, N);

  // ---- layer 1: GEMM1 -> agg -> stats -> fin ----
  k_gemm_mfma<256,128,true,false,true,false><<<gemm_grid,256,0,stream>>>(P16, Wh1, Wl1, bnsc+0, bnsh+0, nullptr, dinv, Q16, nullptr, N);
  k_agg16<<<(N*16+255)/256,256,0,stream>>>(Q16, rowptr, adj, dinv, b1, R16, N, 4);
  k_bn_stats16<<<BN_G1,256,0,stream>>>(R16, partials, N, 7);
  k_bn_fin<<<2,64,0,stream>>>(partials, 128, BN_G1, g1, be1, bnsc+256, bnsh+256, N);

  // ---- layer 2: GEMM2 -> agg -> stats -> fin ----
  k_gemm_mfma<128,64,true,false,true,false><<<gemm_grid,256,0,stream>>>(R16, Wh2, Wl2, bnsc+256, bnsh+256, nullptr, dinv, Q16, nullptr, N);
  k_agg16<<<(N*8+255)/256,256,0,stream>>>(Q16, rowptr, adj, dinv, b2, O16, N, 3);
  k_bn_stats16<<<BN_G1,256,0,stream>>>(O16, partials, N, 6);
  k_bn_fin<<<1,64,0,stream>>>(partials, 64, BN_G1, g2, be2, bnsc+512, bnsh+512, N);

  // ---- head ----
  k_ln_att<<<1024,256,0,stream>>>(O16, bnsc+512, bnsh+512, ln_g, ln_b, att, LNX, WV, Ssum, N);
  k_pool  <<<(N+511)/512,256,0,stream>>>(LNX, WV, batch, psum, N);
  k_mlp   <<<1,64,0,stream>>>(psum, cnt, Ssum, M0W,M0b,M1W,M1b,M2W,M2b, (float*)d_out);
}

// Round 18
// 553.872 us; speedup vs baseline: 2.1749x; 2.1749x over previous
//
#include <hip/hip_runtime.h>
#include <hip/hip_bf16.h>
#include <cstdint>
#include <cstddef>

typedef float    f32x4  __attribute__((ext_vector_type(4)));
typedef _Float16 f16x4  __attribute__((ext_vector_type(4)));
typedef _Float16 f16x8  __attribute__((ext_vector_type(8)));

#define BN_G1 1024   // stage-1 grid for standalone bn stats

// ---------------- graph structure ----------------
__global__ void k_hist(const int* __restrict__ dst, int* __restrict__ deg, int E,
                       unsigned long long M,
                       const int* __restrict__ batch, int* __restrict__ cnt, int n){
  __shared__ int h[64];
  if(threadIdx.x<64) h[threadIdx.x]=0;
  __syncthreads();
  int f   = blockIdx.x & 7;
  int cid = blockIdx.x >> 3;
  int nch = gridDim.x >> 3;
  for(int i = cid*blockDim.x + threadIdx.x; i < E; i += nch*blockDim.x){
    int d = dst[i];
    int xf = (int)(((unsigned long long)(unsigned)d * M) >> 40);
    if(xf == f) atomicAdd(&deg[d], 1);
  }
  for(int i = blockIdx.x*blockDim.x + threadIdx.x; i < n; i += gridDim.x*blockDim.x)
    atomicAdd(&h[batch[i]], 1);
  __syncthreads();
  if(threadIdx.x<64 && h[threadIdx.x]) atomicAdd(&cnt[threadIdx.x], h[threadIdx.x]);
}

__global__ void k_scan1(const int* __restrict__ deg, int* __restrict__ bsum, int n){
  __shared__ int s[256];
  int base = blockIdx.x*1024 + threadIdx.x*4;
  int acc=0;
  #pragma unroll
  for(int j=0;j<4;j++){ int i=base+j; if(i<n) acc+=deg[i]; }
  s[threadIdx.x]=acc; __syncthreads();
  for(int off=128;off>0;off>>=1){
    if(threadIdx.x<off) s[threadIdx.x]+=s[threadIdx.x+off];
    __syncthreads();
  }
  if(threadIdx.x==0) bsum[blockIdx.x]=s[0];
}

__global__ void k_scan2(int* __restrict__ bsum, int nblk, int* __restrict__ rowptr, int n){
  __shared__ int s[128];
  int t=threadIdx.x;
  int v = (t<nblk)? bsum[t] : 0;
  s[t]=v; __syncthreads();
  for(int off=1; off<128; off<<=1){
    int a = (t>=off)? s[t-off] : 0;
    __syncthreads();
    s[t]+=a;
    __syncthreads();
  }
  if(t<nblk) bsum[t]=s[t]-v;
  if(t==127) rowptr[n]=s[127];
}

__global__ void k_scan3(const int* __restrict__ deg, const int* __restrict__ bsum,
                        int* __restrict__ rowptr, int* __restrict__ cursor, int n){
  __shared__ int s[256];
  int base = blockIdx.x*1024 + threadIdx.x*4;
  int v[4]; int acc=0;
  #pragma unroll
  for(int j=0;j<4;j++){ int i=base+j; v[j]=(i<n)?deg[i]:0; acc+=v[j]; }
  s[threadIdx.x]=acc; __syncthreads();
  for(int off=1; off<256; off<<=1){
    int a = (threadIdx.x>=off)? s[threadIdx.x-off] : 0;
    __syncthreads();
    s[threadIdx.x]+=a;
    __syncthreads();
  }
  int excl = s[threadIdx.x]-acc + bsum[blockIdx.x];
  #pragma unroll
  for(int j=0;j<4;j++){
    int i=base+j;
    if(i<n){ rowptr[i]=excl; cursor[i]=excl; excl+=v[j]; }
  }
}

__global__ void k_csr_fill(const int* __restrict__ src, const int* __restrict__ dst,
                           int* __restrict__ cursor, int* __restrict__ adj, int E,
                           unsigned long long M){
  int f   = blockIdx.x & 7;
  int cid = blockIdx.x >> 3;
  int nch = gridDim.x >> 3;
  for(int i = cid*blockDim.x + threadIdx.x; i < E; i += nch*blockDim.x){
    int d = dst[i];
    int xf = (int)(((unsigned long long)(unsigned)d * M) >> 40);
    if(xf == f){
      int p = atomicAdd(&cursor[d], 1);
      adj[p] = src[i];
    }
  }
}

// ---------------- fused prep: W hi/lo split (3 mats) + dinv + x16 ----------------
__global__ void k_prep(const float* __restrict__ W0, const float* __restrict__ W1,
                       const float* __restrict__ W2,
                       _Float16* __restrict__ Wh0, _Float16* __restrict__ Wl0,
                       _Float16* __restrict__ Wh1, _Float16* __restrict__ Wl1,
                       _Float16* __restrict__ Wh2, _Float16* __restrict__ Wl2,
                       const float* __restrict__ x, const int* __restrict__ deg,
                       float* __restrict__ dinv, _Float16* __restrict__ x16, int n){
  int i = blockIdx.x*256 + threadIdx.x;
  if(i < 73728){
    const float* W; _Float16 *Wh, *Wl; int K, F, idx;
    if(i < 32768){        W=W0; Wh=Wh0; Wl=Wl0; K=128; F=256; idx=i; }
    else if(i < 65536){   W=W1; Wh=Wh1; Wl=Wl1; K=256; F=128; idx=i-32768; }
    else {                W=W2; Wh=Wh2; Wl=Wl2; K=128; F=64;  idx=i-65536; }
    int k = idx / F, f = idx % F;
    float a = W[idx];
    _Float16 h = (_Float16)a;
    Wh[(size_t)f*K + k] = h;
    Wl[(size_t)f*K + k] = (_Float16)(a - (float)h);
    return;
  }
  int tid = i - 73728;
  int node = tid >> 5;
  if(node>=n) return;
  int c4 = tid & 31;
  float d = rsqrtf((float)(deg[node]+1));
  if(c4==0) dinv[node] = d;
  size_t idx = ((size_t)node<<5) + c4;
  float4 v = ((const float4*)x)[idx];
  f16x4 o;
  o[0]=(_Float16)(v.x*d); o[1]=(_Float16)(v.y*d); o[2]=(_Float16)(v.z*d); o[3]=(_Float16)(v.w*d);
  ((f16x4*)x16)[idx] = o;
}

// ---------------- aggregate (fp16 gather, fp32 accum, fp16 out; barrier-free) ----------------
__global__ void k_agg16(const _Float16* __restrict__ zs, const int* __restrict__ rowptr,
                        const int* __restrict__ adj, const float* __restrict__ dinv,
                        const float* __restrict__ bias, _Float16* __restrict__ out,
                        int n, int lg8){
  int tid = blockIdx.x*blockDim.x + threadIdx.x;
  int node = tid >> lg8;
  if(node>=n) return;
  int c8 = tid & ((1<<lg8)-1);
  const f16x8* z8 = (const f16x8*)zs;
  size_t rb = ((size_t)node<<lg8) + c8;
  f16x8 self = z8[rb];
  float a0[8], a1[8], a2[8], a3[8];
  #pragma unroll
  for(int j=0;j<8;j++){ a0[j]=(float)self[j]; a1[j]=0.f; a2[j]=0.f; a3[j]=0.f; }
  int e = rowptr[node], end = rowptr[node+1];
  for(; e+3<end; e+=4){
    int s0=adj[e], s1=adj[e+1], s2=adj[e+2], s3=adj[e+3];
    f16x8 v0 = z8[((size_t)s0<<lg8)+c8];
    f16x8 v1 = z8[((size_t)s1<<lg8)+c8];
    f16x8 v2 = z8[((size_t)s2<<lg8)+c8];
    f16x8 v3 = z8[((size_t)s3<<lg8)+c8];
    #pragma unroll
    for(int j=0;j<8;j++){
      a0[j]+=(float)v0[j]; a1[j]+=(float)v1[j];
      a2[j]+=(float)v2[j]; a3[j]+=(float)v3[j];
    }
  }
  for(; e<end; e++){
    f16x8 v0 = z8[((size_t)adj[e]<<lg8)+c8];
    #pragma unroll
    for(int j=0;j<8;j++) a0[j]+=(float)v0[j];
  }
  float di = dinv[node];
  f16x8 o;
  #pragma unroll
  for(int j=0;j<8;j++){
    float r = ((a0[j]+a1[j])+(a2[j]+a3[j]))*di;
    if(bias) r += bias[(c8<<3)+j];
    o[j] = (_Float16)r;
  }
  ((f16x8*)out)[rb] = o;
}

// ---------------- MFMA GEMM: f16 A, f16 hi/lo B, LDS-staged B, optional fused stats ----------------
template<int K, int F, bool BN, bool BIAS, bool RSC, bool STATS>
__global__ __launch_bounds__(256,2) void k_gemm_mfma(const _Float16* __restrict__ A,
    const _Float16* __restrict__ Bh, const _Float16* __restrict__ Bl,
    const float* __restrict__ sc, const float* __restrict__ sh,
    const float* __restrict__ bias, const float* __restrict__ rsc,
    _Float16* __restrict__ C, float* __restrict__ partials, int n){
  constexpr int NF = F/16;
  __shared__ uint4 sBh[F*4];
  __shared__ uint4 sBl[F*4];
  const int l   = threadIdx.x & 63;
  const int w   = threadIdx.x >> 6;
  const int rlo = l & 15;
  const int khi = l >> 4;
  const int row0 = blockIdx.x*128 + w*32;

  f32x4 acc[2][NF];
  #pragma unroll
  for(int i=0;i<2;i++)
    #pragma unroll
    for(int j=0;j<NF;j++) acc[i][j] = (f32x4){0.f,0.f,0.f,0.f};

  const size_t e0 = (size_t)min(row0 + rlo,      n-1) * K + khi*8;
  const size_t e1 = (size_t)min(row0 + 16 + rlo, n-1) * K + khi*8;

  f16x8 c0 = *(const f16x8*)(A + e0);
  f16x8 c1 = *(const f16x8*)(A + e1);
  f16x8 n0v, n1v;

  #pragma unroll 1
  for(int k0=0; k0<K; k0+=32){
    if(k0+32 < K){
      n0v = *(const f16x8*)(A + e0 + k0 + 32);
      n1v = *(const f16x8*)(A + e1 + k0 + 32);
    }
    __syncthreads();
    #pragma unroll
    for(int j=0;j<F/64;j++){
      int i  = threadIdx.x + j*256;
      int f  = i >> 2;
      int k8 = i & 3;
      int g  = ((f>>4)<<6) + (k8<<4) + (f&15);
      size_t goff = (size_t)f*K + k0 + (k8<<3);
      sBh[g] = *(const uint4*)(Bh + goff);
      sBl[g] = *(const uint4*)(Bl + goff);
    }
    f16x8 a0, a1;
    if(BN){
      float scr[8], shr[8];
      float4 s0 = *(const float4*)(sc + k0 + khi*8);
      float4 s1 = *(const float4*)(sc + k0 + khi*8 + 4);
      float4 t0 = *(const float4*)(sh + k0 + khi*8);
      float4 t1 = *(const float4*)(sh + k0 + khi*8 + 4);
      scr[0]=s0.x;scr[1]=s0.y;scr[2]=s0.z;scr[3]=s0.w;scr[4]=s1.x;scr[5]=s1.y;scr[6]=s1.z;scr[7]=s1.w;
      shr[0]=t0.x;shr[1]=t0.y;shr[2]=t0.z;shr[3]=t0.w;shr[4]=t1.x;shr[5]=t1.y;shr[6]=t1.z;shr[7]=t1.w;
      #pragma unroll
      for(int j=0;j<8;j++){
        a0[j] = (_Float16)fmaxf(fmaf((float)c0[j],scr[j],shr[j]),0.f);
        a1[j] = (_Float16)fmaxf(fmaf((float)c1[j],scr[j],shr[j]),0.f);
      }
    }else{
      a0 = c0; a1 = c1;
    }
    __syncthreads();
    #pragma unroll
    for(int cf=0; cf<NF; cf++){
      f16x8 bh = ((const f16x8*)sBh)[cf*64 + l];
      f16x8 bl = ((const f16x8*)sBl)[cf*64 + l];
      acc[0][cf] = __builtin_amdgcn_mfma_f32_16x16x32_f16(a0, bh, acc[0][cf], 0,0,0);
      acc[1][cf] = __builtin_amdgcn_mfma_f32_16x16x32_f16(a1, bh, acc[1][cf], 0,0,0);
      acc[0][cf] = __builtin_amdgcn_mfma_f32_16x16x32_f16(a0, bl, acc[0][cf], 0,0,0);
      acc[1][cf] = __builtin_amdgcn_mfma_f32_16x16x32_f16(a1, bl, acc[1][cf], 0,0,0);
    }
    c0=n0v; c1=n1v;
  }

  float ts[NF], ts2[NF];
  if constexpr(STATS){
    #pragma unroll
    for(int cf=0;cf<NF;cf++){ ts[cf]=0.f; ts2[cf]=0.f; }
  }
  #pragma unroll
  for(int rf=0; rf<2; rf++){
    #pragma unroll
    for(int r=0; r<4; r++){
      int m = row0 + rf*16 + khi*4 + r;
      if(m < n){
        float rscv = RSC ? rsc[m] : 1.f;
        #pragma unroll
        for(int cf=0; cf<NF; cf++){
          int col = rlo + 16*cf;
          float v = acc[rf][cf][r];
          if(BIAS) v += bias[col];
          v *= rscv;
          C[(size_t)m*F + col] = (_Float16)v;
          if constexpr(STATS){ ts[cf]+=v; ts2[cf]=fmaf(v,v,ts2[cf]); }
        }
      }
    }
  }
  if constexpr(STATS){
    __shared__ float sstat[4][16][NF][2];
    #pragma unroll
    for(int cf=0;cf<NF;cf++){
      ts [cf] += __shfl_xor(ts [cf],16); ts [cf] += __shfl_xor(ts [cf],32);
      ts2[cf] += __shfl_xor(ts2[cf],16); ts2[cf] += __shfl_xor(ts2[cf],32);
    }
    if(khi==0){
      #pragma unroll
      for(int cf=0;cf<NF;cf++){ sstat[w][rlo][cf][0]=ts[cf]; sstat[w][rlo][cf][1]=ts2[cf]; }
    }
    __syncthreads();
    {
      int rl = threadIdx.x & 15, cf = threadIdx.x >> 4;
      float s_=0.f, s2_=0.f;
      #pragma unroll
      for(int ww=0; ww<4; ww++){ s_+=sstat[ww][rl][cf][0]; s2_+=sstat[ww][rl][cf][1]; }
      int col = rl + 16*cf;
      partials[(size_t)blockIdx.x*(2*F) + col]     = s_;
      partials[(size_t)blockIdx.x*(2*F) + F + col] = s2_;
    }
  }
}

// ---------------- standalone BN stats (fp16 in, per-block partials out) ----------------
__global__ __launch_bounds__(256) void k_bn_stats16(const _Float16* __restrict__ h,
                            float* __restrict__ partials, int n, int lgF){
  const int F   = 1 << lgF;
  const int C8  = 1 << (lgF-3);
  const int c8  = threadIdx.x & (C8-1);
  const int sub = threadIdx.x >> (lgF-3);
  const int rpb = 256 >> (lgF-3);
  float s[8], s2[8];
  #pragma unroll
  for(int j=0;j<8;j++){ s[j]=0.f; s2[j]=0.f; }
  for(int row = blockIdx.x*rpb + sub; row < n; row += gridDim.x*rpb){
    f16x8 v = ((const f16x8*)h)[(size_t)row*C8 + c8];
    #pragma unroll
    for(int j=0;j<8;j++){ float f=(float)v[j]; s[j]+=f; s2[j]=fmaf(f,f,s2[j]); }
  }
  __shared__ float rs [256*9];
  __shared__ float rs2[256*9];
  #pragma unroll
  for(int j=0;j<8;j++){ rs[threadIdx.x*9+j]=s[j]; rs2[threadIdx.x*9+j]=s2[j]; }
  __syncthreads();
  for(int half = rpb>>1; half>=1; half>>=1){
    if(sub < half){
      int o = (threadIdx.x + half*C8)*9;
      #pragma unroll
      for(int j=0;j<8;j++){ rs[threadIdx.x*9+j]+=rs[o+j]; rs2[threadIdx.x*9+j]+=rs2[o+j]; }
    }
    __syncthreads();
  }
  if(sub==0){
    float* p = partials + (size_t)blockIdx.x*(2*F);
    #pragma unroll
    for(int j=0;j<8;j++){
      p[c8*8+j]     = rs [threadIdx.x*9+j];
      p[F + c8*8+j] = rs2[threadIdx.x*9+j];
    }
  }
}

// ---------------- BN reduction (two-stage, 64-way sliced) ----------------
// grid (F2/64, 64), block 64
__global__ void k_colsum1(const float* __restrict__ partials, float* __restrict__ lvl1,
                          int F2, int nblk){
  int c = blockIdx.x*64 + threadIdx.x;
  int slice = blockIdx.y;
  int b0 = (int)(((long long)nblk *  slice   ) >> 6);
  int b1 = (int)(((long long)nblk * (slice+1)) >> 6);
  float s = 0.f;
  for(int b=b0; b<b1; b++) s += partials[(size_t)b*F2 + c];
  lvl1[slice*F2 + c] = s;
}

// grid F/64, block 64: sum 64 lvl1 rows + finalize scale/shift
__global__ void k_bn_fin2(const float* __restrict__ lvl1, int F,
                          const float* __restrict__ g, const float* __restrict__ be,
                          float* __restrict__ scale, float* __restrict__ shift, int n){
  int c = blockIdx.x*64 + threadIdx.x;
  int F2 = 2*F;
  float s=0.f, s2=0.f;
  #pragma unroll
  for(int k=0;k<64;k++){ s += lvl1[k*F2 + c]; s2 += lvl1[k*F2 + F + c]; }
  float mu = s/(float)n;
  float var = s2/(float)n - mu*mu;
  float sc = g[c]*rsqrtf(var+1e-5f);
  scale[c] = sc;
  shift[c] = fmaf(-mu, sc, be[c]);
}

// ---------------- head ----------------
__device__ __forceinline__ float attw(float a){
  float t = fminf(fmaxf(a,-15.f),15.f);
  float u = exp2f(t*2.885390082f);
  float th = (u-1.f)/(u+1.f);
  return exp2f(th*1.442695041f);
}

__global__ void k_ln_att(const _Float16* __restrict__ x, const float* __restrict__ bsc, const float* __restrict__ bsh,
                         const float* __restrict__ g, const float* __restrict__ b,
                         const float* __restrict__ att, _Float16* __restrict__ lnx, float* __restrict__ wv,
                         float* __restrict__ Ssum, int n){
  int lane = threadIdx.x & 63;
  int wid = (blockIdx.x<<2) + (threadIdx.x>>6);
  float gl=g[lane], bl=b[lane], al=att[lane];
  float scl=bsc[lane], shl=bsh[lane];
  float wacc=0.f;
  int node = wid;
  for(; node+4096 < n; node += 8192){
    int n1 = node + 4096;
    float v0 = fmaxf(fmaf((float)x[((size_t)node<<6)+lane], scl, shl), 0.f);
    float v1 = fmaxf(fmaf((float)x[((size_t)n1  <<6)+lane], scl, shl), 0.f);
    float s0=v0, s1=v1;
    #pragma unroll
    for(int o=32;o>0;o>>=1){ s0+=__shfl_xor(s0,o); s1+=__shfl_xor(s1,o); }
    float d0=v0-s0*0.015625f, d1=v1-s1*0.015625f;
    float q0=d0*d0, q1=d1*d1;
    #pragma unroll
    for(int o=32;o>0;o>>=1){ q0+=__shfl_xor(q0,o); q1+=__shfl_xor(q1,o); }
    float ln0 = d0*rsqrtf(q0*0.015625f+1e-5f)*gl+bl;
    float ln1 = d1*rsqrtf(q1*0.015625f+1e-5f)*gl+bl;
    lnx[((size_t)node<<6)+lane]=(_Float16)ln0;
    lnx[((size_t)n1  <<6)+lane]=(_Float16)ln1;
    float a0=ln0*al, a1=ln1*al;
    #pragma unroll
    for(int o=32;o>0;o>>=1){ a0+=__shfl_xor(a0,o); a1+=__shfl_xor(a1,o); }
    float w0=attw(a0), w1=attw(a1);
    if(lane==0){ wv[node]=w0; wv[n1]=w1; }
    wacc += w0+w1;
  }
  for(; node<n; node+=4096){
    float v0 = fmaxf(fmaf((float)x[((size_t)node<<6)+lane], scl, shl), 0.f);
    float s0=v0;
    #pragma unroll
    for(int o=32;o>0;o>>=1) s0+=__shfl_xor(s0,o);
    float d0=v0-s0*0.015625f;
    float q0=d0*d0;
    #pragma unroll
    for(int o=32;o>0;o>>=1) q0+=__shfl_xor(q0,o);
    float ln0 = d0*rsqrtf(q0*0.015625f+1e-5f)*gl+bl;
    lnx[((size_t)node<<6)+lane]=(_Float16)ln0;
    float a0=ln0*al;
    #pragma unroll
    for(int o=32;o>0;o>>=1) a0+=__shfl_xor(a0,o);
    float w0=attw(a0);
    if(lane==0) wv[node]=w0;
    wacc += w0;
  }
  __shared__ float sred[4];
  if(lane==0) sred[threadIdx.x>>6]=wacc;
  __syncthreads();
  if(threadIdx.x==0) atomicAdd(Ssum, sred[0]+sred[1]+sred[2]+sred[3]);
}

__global__ void k_pool(const _Float16* __restrict__ lnx, const float* __restrict__ wv,
                       const int* __restrict__ batch, float* __restrict__ psum, int n){
  int lane = threadIdx.x & 63;
  int wave = threadIdx.x >> 6;
  int start = blockIdx.x*512 + wave*128;
  if(start >= n) return;
  int end = min(start+128, n);
  int cur = batch[start];
  float acc = 0.f;
  for(int i=start;i<end;i++){
    int bb = batch[i];
    if(bb != cur){ atomicAdd(&psum[cur*64+lane], acc); acc=0.f; cur=bb; }
    acc = fmaf((float)lnx[(size_t)i*64+lane], wv[i], acc);
  }
  atomicAdd(&psum[cur*64+lane], acc);
}

__global__ void k_mlp(const float* __restrict__ psum, const int* __restrict__ cnt,
                      const float* __restrict__ Ssum,
                      const float* __restrict__ M0W, const float* __restrict__ M0b,
                      const float* __restrict__ M1W, const float* __restrict__ M1b,
                      const float* __restrict__ M2W, const float* __restrict__ M2b,
                      float* __restrict__ out){
  int b = threadIdx.x;
  float S = Ssum[0];
  int cb = cnt[b]; if(cb<1) cb=1;
  float inv = 1.f/(S*(float)cb);
  float p[64];
  #pragma unroll
  for(int f=0;f<64;f++) p[f] = psum[b*64+f]*inv;
  float h1[32];
  #pragma unroll
  for(int j=0;j<32;j++){
    float a=M0b[j];
    #pragma unroll
    for(int f=0;f<64;f++) a = fmaf(p[f], M0W[f*32+j], a);
    h1[j]=fmaxf(a,0.f);
  }
  float h2[16];
  #pragma unroll
  for(int j=0;j<16;j++){
    float a=M1b[j];
    #pragma unroll
    for(int f=0;f<32;f++) a = fmaf(h1[f], M1W[f*16+j], a);
    h2[j]=fmaxf(a,0.f);
  }
  #pragma unroll
  for(int j=0;j<2;j++){
    float a=M2b[j];
    #pragma unroll
    for(int f=0;f<16;f++) a = fmaf(h2[f], M2W[f*2+j], a);
    out[b*2+j]=a;
  }
}

// ---------------- launch ----------------

extern "C" void kernel_launch(void* const* d_in, const int* in_sizes, int n_in,
                              void* d_out, int out_size, void* d_ws, size_t ws_size,
                              hipStream_t stream){
  const float* x   = (const float*)d_in[0];
  const int*   ei  = (const int*)d_in[1];
  const int* batch = (const int*)d_in[2];
  const float* W0=(const float*)d_in[3],  *b0=(const float*)d_in[4],  *g0=(const float*)d_in[5],  *be0=(const float*)d_in[6];
  const float* W1=(const float*)d_in[7],  *b1=(const float*)d_in[8],  *g1=(const float*)d_in[9],  *be1=(const float*)d_in[10];
  const float* W2=(const float*)d_in[11], *b2=(const float*)d_in[12], *g2=(const float*)d_in[13], *be2=(const float*)d_in[14];
  const float* ln_g=(const float*)d_in[15], *ln_b=(const float*)d_in[16], *att=(const float*)d_in[17];
  const float* M0W=(const float*)d_in[18], *M0b=(const float*)d_in[19];
  const float* M1W=(const float*)d_in[20], *M1b=(const float*)d_in[21];
  const float* M2W=(const float*)d_in[22], *M2b=(const float*)d_in[23];
  const int N = in_sizes[0]/128;
  const int E = in_sizes[1]/2;
  const int* srcv = ei;
  const int* dstv = ei + E;
  const unsigned long long Mdiv = ((8ULL<<40) + (unsigned long long)N - 1) / (unsigned long long)N;

  const int gemm_grid = (N+127)/128;

  char* base = (char*)d_ws;
  size_t off = 0;
  auto alloc = [&](size_t bytes)->char*{ char* p = base+off; off = (off+bytes+255)&~(size_t)255; return p; };
  // zeroed region first
  int*   deg    = (int*)  alloc((size_t)N*4);
  int*   cnt    = (int*)  alloc(64*4);
  float* psum   = (float*)alloc(64*64*4);
  float* Ssum   = (float*)alloc(4);
  size_t zero_bytes = off;
  float* dinv   = (float*)alloc((size_t)N*4);
  int*   rowptr = (int*)  alloc(((size_t)N+1)*4);
  int*   cursor = (int*)  alloc((size_t)N*4);
  int*   bsum   = (int*)  alloc(128*4);
  float* bnsc   = (float*)alloc(3*256*4);
  float* bnsh   = (float*)alloc(3*256*4);
  float* partials = (float*)alloc((size_t)BN_G1*512*4);
  float* lvl1   = (float*)alloc((size_t)64*512*4);
  _Float16* Wh0 = (_Float16*)alloc((size_t)128*256*2);
  _Float16* Wl0 = (_Float16*)alloc((size_t)128*256*2);
  _Float16* Wh1 = (_Float16*)alloc((size_t)256*128*2);
  _Float16* Wl1 = (_Float16*)alloc((size_t)256*128*2);
  _Float16* Wh2 = (_Float16*)alloc((size_t)128*64*2);
  _Float16* Wl2 = (_Float16*)alloc((size_t)128*64*2);
  int*   adj    = (int*)  alloc((size_t)E*4);
  _Float16* x16 = (_Float16*)alloc((size_t)N*128*2);
  _Float16* R16 = (_Float16*)alloc((size_t)N*128*2);
  _Float16* P16 = (_Float16*)alloc((size_t)N*256*2);
  _Float16* Q16 = (_Float16*)alloc((size_t)N*128*2);
  _Float16* O16 = (_Float16*)alloc((size_t)N*64*2);
  _Float16* LNX = (_Float16*)alloc((size_t)N*64*2);
  float* WV     = (float*)alloc((size_t)N*4);
  (void)ws_size; (void)n_in; (void)out_size;

  hipMemsetAsync(d_ws, 0, zero_bytes, stream);

  // graph structure + fused prep
  k_hist <<<2048,256,0,stream>>>(dstv, deg, E, Mdiv, batch, cnt, N);
  k_prep <<<(73728 + N*32 + 255)/256,256,0,stream>>>(W0,W1,W2, Wh0,Wl0, Wh1,Wl1, Wh2,Wl2,
                                                     x, deg, dinv, x16, N);
  int nblk = (N+1023)/1024;
  k_scan1<<<nblk,256,0,stream>>>(deg, bsum, N);
  k_scan2<<<1,128,0,stream>>>(bsum, nblk, rowptr, N);
  k_scan3<<<nblk,256,0,stream>>>(deg, bsum, rowptr, cursor, N);
  k_csr_fill<<<2048,256,0,stream>>>(srcv, dstv, cursor, adj, E, Mdiv);

  // ---- layer 0: agg -> GEMM0(+fused stats) -> colsum/fin ----
  k_agg16<<<(N*16+255)/256,256,0,stream>>>(x16, rowptr, adj, dinv, nullptr, R16, N, 4);
  k_gemm_mfma<128,256,false,true,false,true><<<gemm_grid,256,0,stream>>>(R16, Wh0, Wl0, nullptr,nullptr, b0, nullptr, P16, partials, N);
  k_colsum1<<<dim3(8,64),64,0,stream>>>(partials, lvl1, 512, gemm_grid);
  k_bn_fin2<<<4,64,0,stream>>>(lvl1, 256, g0, be0, bnsc+0, bnsh+0, N);

  // ---- layer 1: GEMM1 -> agg -> stats -> colsum/fin ----
  k_gemm_mfma<256,128,true,false,true,false><<<gemm_grid,256,0,stream>>>(P16, Wh1, Wl1, bnsc+0, bnsh+0, nullptr, dinv, Q16, nullptr, N);
  k_agg16<<<(N*16+255)/256,256,0,stream>>>(Q16, rowptr, adj, dinv, b1, R16, N, 4);
  k_bn_stats16<<<BN_G1,256,0,stream>>>(R16, partials, N, 7);
  k_colsum1<<<dim3(4,64),64,0,stream>>>(partials, lvl1, 256, BN_G1);
  k_bn_fin2<<<2,64,0,stream>>>(lvl1, 128, g1, be1, bnsc+256, bnsh+256, N);

  // ---- layer 2: GEMM2 -> agg -> stats -> colsum/fin ----
  k_gemm_mfma<128,64,true,false,true,false><<<gemm_grid,256,0,stream>>>(R16, Wh2, Wl2, bnsc+256, bnsh+256, nullptr, dinv, Q16, nullptr, N);
  k_agg16<<<(N*8+255)/256,256,0,stream>>>(Q16, rowptr, adj, dinv, b2, O16, N, 3);
  k_bn_stats16<<<BN_G1,256,0,stream>>>(O16, partials, N, 6);
  k_colsum1<<<dim3(2,64),64,0,stream>>>(partials, lvl1, 128, BN_G1);
  k_bn_fin2<<<1,64,0,stream>>>(lvl1, 64, g2, be2, bnsc+512, bnsh+512, N);

  // ---- head ----
  k_ln_att<<<1024,256,0,stream>>>(O16, bnsc+512, bnsh+512, ln_g, ln_b, att, LNX, WV, Ssum, N);
  k_pool  <<<(N+511)/512,256,0,stream>>>(LNX, WV, batch, psum, N);
  k_mlp   <<<1,64,0,stream>>>(psum, cnt, Ssum, M0W,M0b,M1W,M1b,M2W,M2b, (float*)d_out);
}